// Round 5
// baseline (200.489 us; speedup 1.0000x reference)
//
#include <hip/hip_runtime.h>
#include <math.h>
#include <string.h>

#define TPB   1024
#define KPT   16          // keys per thread (n = TPB*KPT = 16384)
#define CAP   2048        // candidate list capacity
#define WAVES (TPB/64)

// ---------------- boost precompute: boost = f32(exp(f64(1.5f*(0.02f - dc)))) ----
__global__ void boost_kernel(const float* __restrict__ dc, float* __restrict__ boost, int n) {
    int i = blockIdx.x * blockDim.x + threadIdx.x;
    if (i < n) {
        float a = 1.5f * (0.02f - dc[i]);   // exact f32 arithmetic, same as reference
        boost[i] = (float)exp((double)a);   // correctly-rounded f32 exp via f64
    }
}

// monotone float -> uint32 key (no NaNs in input)
__device__ __forceinline__ unsigned fkey(float f) {
    unsigned u = __float_as_uint(f);
    return (u & 0x80000000u) ? ~u : (u | 0x80000000u);
}

// wave-wide sum of per-lane count c (0..63) via bit-plane ballots; uniform result.
__device__ __forceinline__ int wave_sum6(int c) {
    int t;
    t  = (int)__popcll(__ballot(c & 1));
    t += (int)__popcll(__ballot(c & 2))  << 1;
    t += (int)__popcll(__ballot(c & 4))  << 2;
    t += (int)__popcll(__ballot(c & 8))  << 3;
    t += (int)__popcll(__ballot(c & 16)) << 4;
    t += (int)__popcll(__ballot(c & 32)) << 5;
    return t;
}

template<bool USE_B>
__global__ __launch_bounds__(TPB, 8)   // <=64 VGPR -> 2 blocks/CU
void kwta_kernel(const float* __restrict__ x,
                 const float* __restrict__ boost,
                 const float* __restrict__ dc,
                 float* __restrict__ out,
                 int n, int k, unsigned PIV) {
    const int tid  = threadIdx.x;
    const int lane = tid & 63;
    const int wave = tid >> 6;
    const int row  = blockIdx.x;

    __shared__ unsigned       s_key[CAP];
    __shared__ unsigned short s_idx[CAP];
    __shared__ int s_cnt[4];
    __shared__ int s_nc;
    __shared__ unsigned s_P;

    if (tid == 0) s_nc = 0;
    if (tid < 4) s_cnt[tid] = 0;

    // ---- dense ZERO write stream: no data dependency, issued first so the
    // memory pipe stays busy through the whole select phase ----
    float4* o4 = (float4*)(out + (size_t)row * n);
    const float4 zz = make_float4(0.f, 0.f, 0.f, 0.f);
    #pragma unroll
    for (int i = 0; i < KPT/4; ++i) o4[tid + i * TPB] = zz;

    // ---- load row, build 16 keys/thread in registers ----
    const float4* x4 = (const float4*)(x + (size_t)row * n);
    unsigned key[KPT];
    if (USE_B) {
        const float4* b4 = (const float4*)boost;
        #pragma unroll
        for (int i = 0; i < KPT/4; ++i) {
            float4 xv = x4[tid + i * TPB];
            float4 bv = b4[tid + i * TPB];
            key[4*i+0] = fkey(xv.x * bv.x);
            key[4*i+1] = fkey(xv.y * bv.y);
            key[4*i+2] = fkey(xv.z * bv.z);
            key[4*i+3] = fkey(xv.w * bv.w);
        }
    } else {
        const float4* d4 = (const float4*)dc;
        #pragma unroll
        for (int i = 0; i < KPT/4; ++i) {
            float4 xv = x4[tid + i * TPB];
            float4 dv = d4[tid + i * TPB];
            key[4*i+0] = fkey(xv.x * (float)exp((double)(1.5f * (0.02f - dv.x))));
            key[4*i+1] = fkey(xv.y * (float)exp((double)(1.5f * (0.02f - dv.y))));
            key[4*i+2] = fkey(xv.z * (float)exp((double)(1.5f * (0.02f - dv.z))));
            key[4*i+3] = fkey(xv.w * (float)exp((double)(1.5f * (0.02f - dv.w))));
        }
    }
    __syncthreads();                         // (a) drains zero-stores; resets visible

    // ---- compact candidates (key >= PIV) with column index ----
    #pragma unroll
    for (int j = 0; j < KPT; ++j) {
        bool e = (key[j] >= PIV);
        unsigned long long m = __ballot(e);
        if (m) {
            int cntm   = (int)__popcll(m);
            int pre    = (int)__popcll(m & ((1ull << lane) - 1ull));
            int leader = __ffsll((long long)m) - 1;
            int base = 0;
            if (lane == leader) base = atomicAdd(&s_nc, cntm);
            base = __shfl(base, leader);
            if (e) {
                int pos = base + pre;
                if (pos < CAP) {
                    s_key[pos] = key[j];
                    s_idx[pos] = (unsigned short)(((tid + (j >> 2) * TPB) << 2) + (j & 3));
                }
            }
        }
    }
    __syncthreads();                         // (b) candidates + nc visible
    const int nc = s_nc;

    if (nc >= k && nc <= CAP) {
        // ---- fast path: one wave (SIMD-spread by row) exact bisect, 2 bits/round ----
        if (wave == (row & (WAVES - 1))) {
            const int mrd = (nc + 63) >> 6;
            unsigned Q = 0;
            for (int b = 30; b >= 0; b -= 2) {
                const unsigned CA = Q | (1u << (b + 1));
                const unsigned CB = Q | (1u << b);
                const unsigned CC = CA | (1u << b);
                int ca = 0, cb = 0, cc = 0;
                for (int j = 0; j < mrd; ++j) {
                    const int idx = lane + (j << 6);
                    const unsigned v = (idx < nc) ? s_key[idx] : 0u;
                    ca += (v >= CA) ? 1 : 0;
                    cb += (v >= CB) ? 1 : 0;
                    cc += (v >= CC) ? 1 : 0;
                }
                const int A = wave_sum6(ca);
                const int B = wave_sum6(cb);
                const int C = wave_sum6(cc);
                if (A >= k)      Q = (C >= k) ? CC : CA;
                else if (B >= k) Q = CB;
            }
            if (lane == 0) s_P = Q;
        }
        __syncthreads();                     // (c) P published; zero-stores long drained
        const unsigned P = s_P;

        // ---- scatter fixup: winners only (~k per row) ----
        for (int t = tid; t < nc; t += TPB)
            if (s_key[t] >= P)
                out[(size_t)row * n + s_idx[t]] = 1.0f;
    } else {
        // ---- fallback: block-wide 32-round bisect + dense rewrite (any data) ----
        int it = 0;
        unsigned P = 0;
        for (int b = 31; b >= 0; --b) {
            const unsigned C = P | (1u << b);
            int c = 0;
            #pragma unroll
            for (int j = 0; j < KPT; ++j) c += (key[j] >= C) ? 1 : 0;
            int t = wave_sum6(c);
            const int s = it & 3;
            if (lane == 0) atomicAdd(&s_cnt[s], t);
            __syncthreads();
            const int total = s_cnt[s];
            if (tid == 0) s_cnt[(s + 2) & 3] = 0;
            ++it;
            if (total >= k) P = C;
        }
        #pragma unroll
        for (int i = 0; i < KPT/4; ++i) {
            float4 o;
            o.x = (key[4*i+0] >= P) ? 1.0f : 0.0f;
            o.y = (key[4*i+1] >= P) ? 1.0f : 0.0f;
            o.z = (key[4*i+2] >= P) ? 1.0f : 0.0f;
            o.w = (key[4*i+3] >= P) ? 1.0f : 0.0f;
            o4[tid + i * TPB] = o;
        }
    }
}

extern "C" void kernel_launch(void* const* d_in, const int* in_sizes, int n_in,
                              void* d_out, int out_size, void* d_ws, size_t ws_size,
                              hipStream_t stream) {
    const float* x  = (const float*)d_in[0];
    const float* dc = (const float*)d_in[1];
    float* out = (float*)d_out;

    int n    = in_sizes[1];             // 16384
    int rows = in_sizes[0] / n;         // 4096
    int k    = (int)llround((double)n * 0.02);
    if (k < 1) k = 1;

    // fixed conservative pivot: xb >= 1.15 -> ~500 candidates/row on this data;
    // block-wide fallback guarantees correctness for any data.
    float pivf = 1.15f;
    unsigned pu;
    memcpy(&pu, &pivf, sizeof(pu));
    unsigned PIV = (pu & 0x80000000u) ? ~pu : (pu | 0x80000000u);

    bool use_ws = (ws_size >= (size_t)n * sizeof(float));
    if (use_ws) {
        float* boost = (float*)d_ws;
        boost_kernel<<<(n + 255) / 256, 256, 0, stream>>>(dc, boost, n);
        kwta_kernel<true><<<rows, TPB, 0, stream>>>(x, boost, dc, out, n, k, PIV);
    } else {
        kwta_kernel<false><<<rows, TPB, 0, stream>>>(x, nullptr, dc, out, n, k, PIV);
    }
}

// Round 6
// 189.290 us; speedup vs baseline: 1.0592x; 1.0592x over previous
//
#include <hip/hip_runtime.h>
#include <math.h>
#include <string.h>

#define CAP   2048        // candidate list capacity (8 KiB LDS)
#define TPA   256         // threads per block, thresh kernel
#define TPM   256         // threads per block, mask kernel
#define TPF   1024        // fused fallback
#define KPTF  16

// ---------------- boost precompute: boost = f32(exp(f64(1.5f*(0.02f - dc)))) ----
__global__ void boost_kernel(const float* __restrict__ dc, float* __restrict__ boost, int n) {
    int i = blockIdx.x * blockDim.x + threadIdx.x;
    if (i < n) {
        float a = 1.5f * (0.02f - dc[i]);   // exact f32 arithmetic, same as reference
        boost[i] = (float)exp((double)a);   // correctly-rounded f32 exp via f64
    }
}

// monotone float -> uint32 key (no NaNs in input)
__device__ __forceinline__ unsigned fkey(float f) {
    unsigned u = __float_as_uint(f);
    return (u & 0x80000000u) ? ~u : (u | 0x80000000u);
}

// wave-wide sum of per-lane count c (0..63) via bit-plane ballots; uniform result.
__device__ __forceinline__ int wave_sum6(int c) {
    int t;
    t  = (int)__popcll(__ballot(c & 1));
    t += (int)__popcll(__ballot(c & 2))  << 1;
    t += (int)__popcll(__ballot(c & 4))  << 2;
    t += (int)__popcll(__ballot(c & 8))  << 3;
    t += (int)__popcll(__ballot(c & 16)) << 4;
    t += (int)__popcll(__ballot(c & 32)) << 5;
    return t;
}

// ================= kernel A: per-row exact threshold (no dense write) =========
__global__ __launch_bounds__(TPA, 8)
void thresh_kernel(const float* __restrict__ x,
                   const float* __restrict__ boost,
                   unsigned* __restrict__ thr,
                   int n, int k, unsigned PIV) {
    const int tid  = threadIdx.x;
    const int lane = tid & 63;
    const int wave = tid >> 6;
    const int row  = blockIdx.x;
    const int IPT  = n / (4 * TPA);          // float4 iters per thread (16)

    __shared__ unsigned s_key[CAP];
    __shared__ int s_cnt[4];
    __shared__ int s_nc;

    if (tid == 0) s_nc = 0;
    if (tid < 4) s_cnt[tid] = 0;
    __syncthreads();                          // resets visible before any append

    const float4* x4 = (const float4*)(x + (size_t)row * n);
    const float4* b4 = (const float4*)boost;

    // ---- stream row, compact keys >= PIV into LDS (keys NOT retained) ----
    #pragma unroll 4
    for (int i = 0; i < IPT; ++i) {
        float4 xv = x4[tid + i * TPA];
        float4 bv = b4[tid + i * TPA];
        unsigned kk[4];
        kk[0] = fkey(xv.x * bv.x);
        kk[1] = fkey(xv.y * bv.y);
        kk[2] = fkey(xv.z * bv.z);
        kk[3] = fkey(xv.w * bv.w);
        #pragma unroll
        for (int j = 0; j < 4; ++j) {
            bool e = (kk[j] >= PIV);
            unsigned long long m = __ballot(e);
            if (m) {
                int cntm   = (int)__popcll(m);
                int pre    = (int)__popcll(m & ((1ull << lane) - 1ull));
                int leader = __ffsll((long long)m) - 1;
                int base = 0;
                if (lane == leader) base = atomicAdd(&s_nc, cntm);
                base = __shfl(base, leader);
                if (e) {
                    int pos = base + pre;
                    if (pos < CAP) s_key[pos] = kk[j];
                }
            }
        }
    }
    __syncthreads();                          // candidates + nc visible
    const int nc = s_nc;

    if (nc >= k && nc <= CAP) {
        // fast path: one wave (SIMD-spread by row) exact bisect, 2 bits/round.
        // Candidate-count == global count for any probe when nc >= k.
        if (wave == (row & 3)) {
            const int mrd = (nc + 63) >> 6;
            unsigned Q = 0;
            for (int b = 30; b >= 0; b -= 2) {
                const unsigned CA = Q | (1u << (b + 1));
                const unsigned CB = Q | (1u << b);
                const unsigned CC = CA | (1u << b);
                int ca = 0, cb = 0, cc = 0;
                for (int j = 0; j < mrd; ++j) {
                    const int idx = lane + (j << 6);
                    const unsigned v = (idx < nc) ? s_key[idx] : 0u;
                    ca += (v >= CA) ? 1 : 0;
                    cb += (v >= CB) ? 1 : 0;
                    cc += (v >= CC) ? 1 : 0;
                }
                const int A = wave_sum6(ca);
                const int B = wave_sum6(cb);
                const int C = wave_sum6(cc);
                if (A >= k)      Q = (C >= k) ? CC : CA;
                else if (B >= k) Q = CB;
            }
            if (lane == 0) thr[row] = Q;
        }
        return;                               // other waves exit; no barrier needed
    }

    // ---- fallback (~never): block-wide 32-round bisect, keys recomputed (L2-hot) ----
    int it = 0;
    unsigned P = 0;
    for (int b = 31; b >= 0; --b) {
        const unsigned C = P | (1u << b);
        int c = 0;
        for (int i = 0; i < IPT; ++i) {
            float4 xv = x4[tid + i * TPA];
            float4 bv = b4[tid + i * TPA];
            c += (fkey(xv.x * bv.x) >= C) ? 1 : 0;
            c += (fkey(xv.y * bv.y) >= C) ? 1 : 0;
            c += (fkey(xv.z * bv.z) >= C) ? 1 : 0;
            c += (fkey(xv.w * bv.w) >= C) ? 1 : 0;
        }
        int t = wave_sum6(c);
        const int s = it & 3;
        if (lane == 0) atomicAdd(&s_cnt[s], t);
        __syncthreads();
        const int total = s_cnt[s];
        if (tid == 0) s_cnt[(s + 2) & 3] = 0;
        ++it;
        if (total >= k) P = C;
    }
    if (tid == 0) thr[row] = P;
}

// ================= kernel B: pure streaming mask ==============================
__global__ __launch_bounds__(TPM, 8)
void mask_kernel(const float* __restrict__ x,
                 const float* __restrict__ boost,
                 const unsigned* __restrict__ thr,
                 float* __restrict__ out, int n) {
    const int tid = threadIdx.x;
    const int row = blockIdx.x;
    const int IPT = n / (4 * TPM);            // 16

    const unsigned P = thr[row];              // wave-uniform -> scalar load
    const float4* x4 = (const float4*)(x + (size_t)row * n);
    const float4* b4 = (const float4*)boost;
    float4* o4 = (float4*)(out + (size_t)row * n);

    #pragma unroll 4
    for (int i = 0; i < IPT; ++i) {
        float4 xv = x4[tid + i * TPM];
        float4 bv = b4[tid + i * TPM];
        float4 o;
        o.x = (fkey(xv.x * bv.x) >= P) ? 1.0f : 0.0f;
        o.y = (fkey(xv.y * bv.y) >= P) ? 1.0f : 0.0f;
        o.z = (fkey(xv.z * bv.z) >= P) ? 1.0f : 0.0f;
        o.w = (fkey(xv.w * bv.w) >= P) ? 1.0f : 0.0f;
        o4[tid + i * TPM] = o;
    }
}

// ================= fused fallback (R4 structure, inline f64 exp) ==============
__global__ __launch_bounds__(TPF, 8)
void kwta_fused(const float* __restrict__ x,
                const float* __restrict__ dc,
                float* __restrict__ out,
                int n, int k, unsigned PIV) {
    const int tid  = threadIdx.x;
    const int lane = tid & 63;
    const int wave = tid >> 6;
    const int row  = blockIdx.x;

    __shared__ unsigned s_list[CAP];
    __shared__ int s_cnt[4];
    __shared__ int s_nc;
    __shared__ unsigned s_P;

    if (tid == 0) s_nc = 0;
    if (tid < 4) s_cnt[tid] = 0;

    const float4* x4 = (const float4*)(x + (size_t)row * n);
    const float4* d4 = (const float4*)dc;
    unsigned key[KPTF];
    #pragma unroll
    for (int i = 0; i < KPTF/4; ++i) {
        float4 xv = x4[tid + i * TPF];
        float4 dv = d4[tid + i * TPF];
        key[4*i+0] = fkey(xv.x * (float)exp((double)(1.5f * (0.02f - dv.x))));
        key[4*i+1] = fkey(xv.y * (float)exp((double)(1.5f * (0.02f - dv.y))));
        key[4*i+2] = fkey(xv.z * (float)exp((double)(1.5f * (0.02f - dv.z))));
        key[4*i+3] = fkey(xv.w * (float)exp((double)(1.5f * (0.02f - dv.w))));
    }
    __syncthreads();

    #pragma unroll
    for (int j = 0; j < KPTF; ++j) {
        bool e = (key[j] >= PIV);
        unsigned long long m = __ballot(e);
        if (m) {
            int cntm   = (int)__popcll(m);
            int pre    = (int)__popcll(m & ((1ull << lane) - 1ull));
            int leader = __ffsll((long long)m) - 1;
            int base = 0;
            if (lane == leader) base = atomicAdd(&s_nc, cntm);
            base = __shfl(base, leader);
            if (e) {
                int pos = base + pre;
                if (pos < CAP) s_list[pos] = key[j];
            }
        }
    }
    __syncthreads();
    const int nc = s_nc;

    unsigned P;
    if (nc >= k && nc <= CAP) {
        if (wave == (row & 15)) {
            const int mrd = (nc + 63) >> 6;
            unsigned Q = 0;
            for (int b = 30; b >= 0; b -= 2) {
                const unsigned CA = Q | (1u << (b + 1));
                const unsigned CB = Q | (1u << b);
                const unsigned CC = CA | (1u << b);
                int ca = 0, cb = 0, cc = 0;
                for (int j = 0; j < mrd; ++j) {
                    const int idx = lane + (j << 6);
                    const unsigned v = (idx < nc) ? s_list[idx] : 0u;
                    ca += (v >= CA) ? 1 : 0;
                    cb += (v >= CB) ? 1 : 0;
                    cc += (v >= CC) ? 1 : 0;
                }
                const int A = wave_sum6(ca);
                const int B = wave_sum6(cb);
                const int C = wave_sum6(cc);
                if (A >= k)      Q = (C >= k) ? CC : CA;
                else if (B >= k) Q = CB;
            }
            if (lane == 0) s_P = Q;
        }
        __syncthreads();
        P = s_P;
    } else {
        int it = 0;
        P = 0;
        for (int b = 31; b >= 0; --b) {
            const unsigned C = P | (1u << b);
            int c = 0;
            #pragma unroll
            for (int j = 0; j < KPTF; ++j) c += (key[j] >= C) ? 1 : 0;
            int t = wave_sum6(c);
            const int s = it & 3;
            if (lane == 0) atomicAdd(&s_cnt[s], t);
            __syncthreads();
            const int total = s_cnt[s];
            if (tid == 0) s_cnt[(s + 2) & 3] = 0;
            ++it;
            if (total >= k) P = C;
        }
    }

    float4* o4 = (float4*)(out + (size_t)row * n);
    #pragma unroll
    for (int i = 0; i < KPTF/4; ++i) {
        float4 o;
        o.x = (key[4*i+0] >= P) ? 1.0f : 0.0f;
        o.y = (key[4*i+1] >= P) ? 1.0f : 0.0f;
        o.z = (key[4*i+2] >= P) ? 1.0f : 0.0f;
        o.w = (key[4*i+3] >= P) ? 1.0f : 0.0f;
        o4[tid + i * TPF] = o;
    }
}

extern "C" void kernel_launch(void* const* d_in, const int* in_sizes, int n_in,
                              void* d_out, int out_size, void* d_ws, size_t ws_size,
                              hipStream_t stream) {
    const float* x  = (const float*)d_in[0];
    const float* dc = (const float*)d_in[1];
    float* out = (float*)d_out;

    int n    = in_sizes[1];             // 16384
    int rows = in_sizes[0] / n;         // 4096
    int k    = (int)llround((double)n * 0.02);
    if (k < 1) k = 1;

    // fixed conservative pivot: xb >= 1.15 -> ~500 candidates/row on this data;
    // exact fallbacks guarantee correctness for any data.
    float pivf = 1.15f;
    unsigned pu;
    memcpy(&pu, &pivf, sizeof(pu));
    unsigned PIV = (pu & 0x80000000u) ? ~pu : (pu | 0x80000000u);

    if (ws_size >= (size_t)(n + rows) * sizeof(float)) {
        float*    boost = (float*)d_ws;
        unsigned* thr   = (unsigned*)d_ws + n;
        boost_kernel<<<(n + 255) / 256, 256, 0, stream>>>(dc, boost, n);
        thresh_kernel<<<rows, TPA, 0, stream>>>(x, boost, thr, n, k, PIV);
        mask_kernel<<<rows, TPM, 0, stream>>>(x, boost, thr, out, n);
    } else {
        kwta_fused<<<rows, TPF, 0, stream>>>(x, dc, out, n, k, PIV);
    }
}

// Round 9
// 117.141 us; speedup vs baseline: 1.7115x; 1.6159x over previous
//
#include <hip/hip_runtime.h>
#include <math.h>
#include <string.h>

#define TPB   256         // threads per block
#define CAP   2048        // candidate list capacity (8 KiB LDS)
#define NW    512         // bitmap words per row (16384 bits)

typedef float f32x4 __attribute__((ext_vector_type(4)));   // native vec for NT store

// ---------------- boost precompute: boost = f32(exp(f64(1.5f*(0.02f - dc)))) ----
__global__ void boost_kernel(const float* __restrict__ dc, float* __restrict__ boost, int n) {
    int i = blockIdx.x * blockDim.x + threadIdx.x;
    if (i < n) {
        float a = 1.5f * (0.02f - dc[i]);   // exact f32 arithmetic, same as reference
        boost[i] = (float)exp((double)a);   // correctly-rounded f32 exp via f64
    }
}

// monotone float -> uint32 key (no NaNs in input)
__device__ __forceinline__ unsigned fkey(float f) {
    unsigned u = __float_as_uint(f);
    return (u & 0x80000000u) ? ~u : (u | 0x80000000u);
}

// wave-wide sum of per-lane count c (0..63) via bit-plane ballots; uniform result.
__device__ __forceinline__ int wave_sum6(int c) {
    int t;
    t  = (int)__popcll(__ballot(c & 1));
    t += (int)__popcll(__ballot(c & 2))  << 1;
    t += (int)__popcll(__ballot(c & 4))  << 2;
    t += (int)__popcll(__ballot(c & 8))  << 3;
    t += (int)__popcll(__ballot(c & 16)) << 4;
    t += (int)__popcll(__ballot(c & 32)) << 5;
    return t;
}

// ============ one-pass kernel: stream-read -> select -> bitmap -> stream-write ====
template<bool USE_B>
__global__ __launch_bounds__(TPB, 8)     // 8 blocks/CU: select windows hide under peers
void kwta_onepass(const float* __restrict__ x,
                  const float* __restrict__ boost,
                  const float* __restrict__ dc,
                  float* __restrict__ out,
                  int n, int k, unsigned PIV) {
    const int tid  = threadIdx.x;
    const int lane = tid & 63;
    const int wave = tid >> 6;
    const int row  = blockIdx.x;
    const int IPT  = n / (4 * TPB);      // 16 float4 iters/thread

    __shared__ unsigned       s_key[CAP];
    __shared__ unsigned short s_idx[CAP];
    __shared__ unsigned       s_bm[NW];
    __shared__ int s_cnt[4];
    __shared__ int s_nc;
    __shared__ unsigned s_P;

    if (tid == 0) s_nc = 0;
    if (tid < 4) s_cnt[tid] = 0;
    s_bm[tid]       = 0;
    s_bm[tid + TPB] = 0;
    __syncthreads();

    const float4* x4 = (const float4*)(x + (size_t)row * n);
    const float4* b4 = (const float4*)boost;
    const float4* d4 = (const float4*)dc;

    // ---- stream row once; compact (key, col) pairs >= PIV into LDS ----
    #pragma unroll 4
    for (int i = 0; i < IPT; ++i) {
        float4 xv = x4[tid + i * TPB];
        unsigned kk[4];
        if (USE_B) {
            float4 bv = b4[tid + i * TPB];
            kk[0] = fkey(xv.x * bv.x);
            kk[1] = fkey(xv.y * bv.y);
            kk[2] = fkey(xv.z * bv.z);
            kk[3] = fkey(xv.w * bv.w);
        } else {
            float4 dv = d4[tid + i * TPB];
            kk[0] = fkey(xv.x * (float)exp((double)(1.5f * (0.02f - dv.x))));
            kk[1] = fkey(xv.y * (float)exp((double)(1.5f * (0.02f - dv.y))));
            kk[2] = fkey(xv.z * (float)exp((double)(1.5f * (0.02f - dv.z))));
            kk[3] = fkey(xv.w * (float)exp((double)(1.5f * (0.02f - dv.w))));
        }
        #pragma unroll
        for (int j = 0; j < 4; ++j) {
            bool e = (kk[j] >= PIV);
            unsigned long long m = __ballot(e);
            if (m) {
                int cntm   = (int)__popcll(m);
                int pre    = (int)__popcll(m & ((1ull << lane) - 1ull));
                int leader = __ffsll((long long)m) - 1;
                int base = 0;
                if (lane == leader) base = atomicAdd(&s_nc, cntm);
                base = __shfl(base, leader);
                if (e) {
                    int pos = base + pre;
                    if (pos < CAP) {
                        s_key[pos] = kk[j];
                        s_idx[pos] = (unsigned short)(4 * (tid + i * TPB) + j);
                    }
                }
            }
        }
    }
    __syncthreads();
    const int nc = s_nc;

    if (nc >= k && nc <= CAP) {
        // ---- fast path: one wave (SIMD-spread by row) exact bisect, 2 bits/round ----
        if (wave == (row & 3)) {
            const int mrd = (nc + 63) >> 6;
            unsigned Q = 0;
            for (int b = 30; b >= 0; b -= 2) {
                const unsigned CA = Q | (1u << (b + 1));
                const unsigned CB = Q | (1u << b);
                const unsigned CC = CA | (1u << b);
                int ca = 0, cb = 0, cc = 0;
                for (int j = 0; j < mrd; ++j) {
                    const int idx = lane + (j << 6);
                    const unsigned v = (idx < nc) ? s_key[idx] : 0u;
                    ca += (v >= CA) ? 1 : 0;
                    cb += (v >= CB) ? 1 : 0;
                    cc += (v >= CC) ? 1 : 0;
                }
                const int A = wave_sum6(ca);
                const int B = wave_sum6(cb);
                const int C = wave_sum6(cc);
                if (A >= k)      Q = (C >= k) ? CC : CA;
                else if (B >= k) Q = CB;
            }
            if (lane == 0) s_P = Q;
        }
        __syncthreads();
        const unsigned P = s_P;

        // ---- set winner bits (~k atomics over the whole block) ----
        for (int t = tid; t < nc; t += TPB)
            if (s_key[t] >= P) {
                const int ix = s_idx[t];
                atomicOr(&s_bm[ix >> 5], 1u << (ix & 31));
            }
        __syncthreads();
    } else {
        // ---- fallback (~never): block-wide bisect, keys recomputed (L2-hot) ----
        int it = 0;
        unsigned P = 0;
        for (int b = 31; b >= 0; --b) {
            const unsigned C = P | (1u << b);
            int c = 0;
            for (int i = 0; i < IPT; ++i) {
                float4 xv = x4[tid + i * TPB];
                unsigned kk[4];
                if (USE_B) {
                    float4 bv = b4[tid + i * TPB];
                    kk[0] = fkey(xv.x * bv.x); kk[1] = fkey(xv.y * bv.y);
                    kk[2] = fkey(xv.z * bv.z); kk[3] = fkey(xv.w * bv.w);
                } else {
                    float4 dv = d4[tid + i * TPB];
                    kk[0] = fkey(xv.x * (float)exp((double)(1.5f * (0.02f - dv.x))));
                    kk[1] = fkey(xv.y * (float)exp((double)(1.5f * (0.02f - dv.y))));
                    kk[2] = fkey(xv.z * (float)exp((double)(1.5f * (0.02f - dv.z))));
                    kk[3] = fkey(xv.w * (float)exp((double)(1.5f * (0.02f - dv.w))));
                }
                c += (kk[0] >= C) + (kk[1] >= C) + (kk[2] >= C) + (kk[3] >= C);
            }
            int t = wave_sum6(c);
            const int s = it & 3;
            if (lane == 0) atomicAdd(&s_cnt[s], t);
            __syncthreads();
            const int total = s_cnt[s];
            if (tid == 0) s_cnt[(s + 2) & 3] = 0;
            ++it;
            if (total >= k) P = C;
        }
        // set winner bits by recompute
        for (int i = 0; i < IPT; ++i) {
            float4 xv = x4[tid + i * TPB];
            unsigned kk[4];
            if (USE_B) {
                float4 bv = b4[tid + i * TPB];
                kk[0] = fkey(xv.x * bv.x); kk[1] = fkey(xv.y * bv.y);
                kk[2] = fkey(xv.z * bv.z); kk[3] = fkey(xv.w * bv.w);
            } else {
                float4 dv = d4[tid + i * TPB];
                kk[0] = fkey(xv.x * (float)exp((double)(1.5f * (0.02f - dv.x))));
                kk[1] = fkey(xv.y * (float)exp((double)(1.5f * (0.02f - dv.y))));
                kk[2] = fkey(xv.z * (float)exp((double)(1.5f * (0.02f - dv.z))));
                kk[3] = fkey(xv.w * (float)exp((double)(1.5f * (0.02f - dv.w))));
            }
            #pragma unroll
            for (int j = 0; j < 4; ++j)
                if (kk[j] >= P) {
                    const int ix = 4 * (tid + i * TPB) + j;
                    atomicOr(&s_bm[ix >> 5], 1u << (ix & 31));
                }
        }
        __syncthreads();
    }

    // ---- dense write from LDS bitmap; nontemporal float4 stream ----
    // float4 index f = s*TPB + tid covers elements 4f..4f+3:
    //   word = (4f)>>5 = s*32 + (tid>>3),  shift = 4*(tid&7)
    f32x4* o4 = (f32x4*)(out + (size_t)row * n);
    const int sh = 4 * (tid & 7);
    #pragma unroll
    for (int s = 0; s < 16; ++s) {
        const unsigned w = s_bm[s * 32 + (tid >> 3)];   // 8-thread broadcast read
        const unsigned b = (w >> sh) & 0xFu;
        f32x4 o;
        o.x = (b & 1u) ? 1.0f : 0.0f;
        o.y = (b & 2u) ? 1.0f : 0.0f;
        o.z = (b & 4u) ? 1.0f : 0.0f;
        o.w = (b & 8u) ? 1.0f : 0.0f;
        __builtin_nontemporal_store(o, &o4[s * TPB + tid]);
    }
}

extern "C" void kernel_launch(void* const* d_in, const int* in_sizes, int n_in,
                              void* d_out, int out_size, void* d_ws, size_t ws_size,
                              hipStream_t stream) {
    const float* x  = (const float*)d_in[0];
    const float* dc = (const float*)d_in[1];
    float* out = (float*)d_out;

    int n    = in_sizes[1];             // 16384
    int rows = in_sizes[0] / n;         // 4096
    int k    = (int)llround((double)n * 0.02);
    if (k < 1) k = 1;

    // fixed conservative pivot: xb >= 1.15 -> ~500 candidates/row on this data;
    // exact fallbacks guarantee correctness for any data.
    float pivf = 1.15f;
    unsigned pu;
    memcpy(&pu, &pivf, sizeof(pu));
    unsigned PIV = (pu & 0x80000000u) ? ~pu : (pu | 0x80000000u);

    if (ws_size >= (size_t)n * sizeof(float)) {
        float* boost = (float*)d_ws;
        boost_kernel<<<(n + 255) / 256, 256, 0, stream>>>(dc, boost, n);
        kwta_onepass<true><<<rows, TPB, 0, stream>>>(x, boost, dc, out, n, k, PIV);
    } else {
        kwta_onepass<false><<<rows, TPB, 0, stream>>>(x, nullptr, dc, out, n, k, PIV);
    }
}

// Round 10
// 111.625 us; speedup vs baseline: 1.7961x; 1.0494x over previous
//
#include <hip/hip_runtime.h>
#include <math.h>
#include <string.h>

#define TPB   512         // threads per block (8 waves)
#define KPT   32          // keys per thread; n = TPB*KPT = 16384
#define CAP   2048        // candidate list capacity (8 KiB LDS)
#define NWAVE (TPB/64)

typedef float f32x4 __attribute__((ext_vector_type(4)));   // native vec for NT store

// ---------------- boost precompute: boost = f32(exp(f64(1.5f*(0.02f - dc)))) ----
__global__ void boost_kernel(const float* __restrict__ dc, float* __restrict__ boost, int n) {
    int i = blockIdx.x * blockDim.x + threadIdx.x;
    if (i < n) {
        float a = 1.5f * (0.02f - dc[i]);   // exact f32 arithmetic, same as reference
        boost[i] = (float)exp((double)a);   // correctly-rounded f32 exp via f64
    }
}

// monotone float -> uint32 key (no NaNs in input)
__device__ __forceinline__ unsigned fkey(float f) {
    unsigned u = __float_as_uint(f);
    return (u & 0x80000000u) ? ~u : (u | 0x80000000u);
}

// wave-wide sum of per-lane count c (0..63) via bit-plane ballots; uniform result.
__device__ __forceinline__ int wave_sum6(int c) {
    int t;
    t  = (int)__popcll(__ballot(c & 1));
    t += (int)__popcll(__ballot(c & 2))  << 1;
    t += (int)__popcll(__ballot(c & 4))  << 2;
    t += (int)__popcll(__ballot(c & 8))  << 3;
    t += (int)__popcll(__ballot(c & 16)) << 4;
    t += (int)__popcll(__ballot(c & 32)) << 5;
    return t;
}

// ======== one-pass: reg-resident keys -> scan-compact -> 1-wave bisect -> reg write ====
template<bool USE_B>
__global__ __launch_bounds__(TPB, 8)    // target <=64 VGPR: 32 waves/CU, 4 blocks/CU
void kwta_scan(const float* __restrict__ x,
               const float* __restrict__ boost,
               const float* __restrict__ dc,
               float* __restrict__ out,
               int n, int k, unsigned PIV) {
    const int tid  = threadIdx.x;
    const int lane = tid & 63;
    const int wave = tid >> 6;
    const int row  = blockIdx.x;

    __shared__ unsigned s_key[CAP];
    __shared__ int s_wtot[NWAVE];
    __shared__ int s_cnt[4];
    __shared__ unsigned s_P;

    // ---- load row, build 32 keys/thread in registers ----
    const float4* x4 = (const float4*)(x + (size_t)row * n);
    const float4* b4 = (const float4*)boost;
    const float4* d4 = (const float4*)dc;
    unsigned key[KPT];
    #pragma unroll
    for (int i = 0; i < KPT/4; ++i) {
        float4 xv = x4[tid + i * TPB];
        if (USE_B) {
            float4 bv = b4[tid + i * TPB];
            key[4*i+0] = fkey(xv.x * bv.x);
            key[4*i+1] = fkey(xv.y * bv.y);
            key[4*i+2] = fkey(xv.z * bv.z);
            key[4*i+3] = fkey(xv.w * bv.w);
        } else {
            float4 dv = d4[tid + i * TPB];
            key[4*i+0] = fkey(xv.x * (float)exp((double)(1.5f * (0.02f - dv.x))));
            key[4*i+1] = fkey(xv.y * (float)exp((double)(1.5f * (0.02f - dv.y))));
            key[4*i+2] = fkey(xv.z * (float)exp((double)(1.5f * (0.02f - dv.z))));
            key[4*i+3] = fkey(xv.w * (float)exp((double)(1.5f * (0.02f - dv.w))));
        }
    }

    // ---- per-thread candidate count (0..32) ----
    int c = 0;
    #pragma unroll
    for (int j = 0; j < KPT; ++j) c += (key[j] >= PIV) ? 1 : 0;

    // ---- wave-level exclusive scan + total via bit-plane ballots (no chain) ----
    const unsigned long long lt = (1ull << lane) - 1ull;
    int pre = 0, wt = 0;
    #pragma unroll
    for (int b = 0; b < 6; ++b) {
        unsigned long long m = __ballot((c >> b) & 1);
        pre += (int)__popcll(m & lt) << b;
        wt  += (int)__popcll(m) << b;
    }
    if (tid < 4) s_cnt[tid] = 0;         // reset for potential fallback
    if (lane == 0) s_wtot[wave] = wt;
    __syncthreads();                     // (1) wave totals visible

    int base = 0, nc = 0;
    #pragma unroll
    for (int w = 0; w < NWAVE; ++w) {
        const int t = s_wtot[w];
        base += (w < wave) ? t : 0;
        nc   += t;
    }
    int off = base + pre;

    // ---- append candidates at scanned offsets (atomic-free) ----
    #pragma unroll
    for (int j = 0; j < KPT; ++j) {
        if (key[j] >= PIV) {
            if (off < CAP) s_key[off] = key[j];
            ++off;
        }
    }
    __syncthreads();                     // (2) candidate list ready

    unsigned P;
    if (nc >= k && nc <= CAP) {
        // ---- fast path: one wave (SIMD-spread by row) exact bisect, 2 bits/round ----
        if (wave == (row & (NWAVE - 1))) {
            const int mrd = (nc + 63) >> 6;
            unsigned Q = 0;
            for (int b = 30; b >= 0; b -= 2) {
                const unsigned CA = Q | (1u << (b + 1));
                const unsigned CB = Q | (1u << b);
                const unsigned CC = CA | (1u << b);
                int ca = 0, cb = 0, cc = 0;
                for (int j = 0; j < mrd; ++j) {
                    const int idx = lane + (j << 6);
                    const unsigned v = (idx < nc) ? s_key[idx] : 0u;  // 0 never >= probe
                    ca += (v >= CA) ? 1 : 0;
                    cb += (v >= CB) ? 1 : 0;
                    cc += (v >= CC) ? 1 : 0;
                }
                const int A = wave_sum6(ca);
                const int B = wave_sum6(cb);
                const int C = wave_sum6(cc);
                if (A >= k)      Q = (C >= k) ? CC : CA;
                else if (B >= k) Q = CB;
            }
            if (lane == 0) s_P = Q;
        }
        __syncthreads();                 // (3) P published
        P = s_P;
    } else {
        // ---- fallback (~never): block-wide 32-round bisect over register keys ----
        int it = 0;
        P = 0;
        for (int b = 31; b >= 0; --b) {
            const unsigned C = P | (1u << b);
            int cc = 0;
            #pragma unroll
            for (int j = 0; j < KPT; ++j) cc += (key[j] >= C) ? 1 : 0;
            int t = wave_sum6(cc);
            const int s = it & 3;
            if (lane == 0) atomicAdd(&s_cnt[s], t);
            __syncthreads();
            const int total = s_cnt[s];
            if (tid == 0) s_cnt[(s + 2) & 3] = 0;
            ++it;
            if (total >= k) P = C;
        }
    }

    // ---- dense write straight from registers; nontemporal float4 stream ----
    f32x4* o4 = (f32x4*)(out + (size_t)row * n);
    #pragma unroll
    for (int i = 0; i < KPT/4; ++i) {
        f32x4 o;
        o.x = (key[4*i+0] >= P) ? 1.0f : 0.0f;
        o.y = (key[4*i+1] >= P) ? 1.0f : 0.0f;
        o.z = (key[4*i+2] >= P) ? 1.0f : 0.0f;
        o.w = (key[4*i+3] >= P) ? 1.0f : 0.0f;
        __builtin_nontemporal_store(o, &o4[tid + i * TPB]);
    }
}

extern "C" void kernel_launch(void* const* d_in, const int* in_sizes, int n_in,
                              void* d_out, int out_size, void* d_ws, size_t ws_size,
                              hipStream_t stream) {
    const float* x  = (const float*)d_in[0];
    const float* dc = (const float*)d_in[1];
    float* out = (float*)d_out;

    int n    = in_sizes[1];             // 16384
    int rows = in_sizes[0] / n;         // 4096
    int k    = (int)llround((double)n * 0.02);
    if (k < 1) k = 1;

    // fixed conservative pivot: xb >= 1.15 -> ~500 candidates/row on this data;
    // exact fallbacks guarantee correctness for any data.
    float pivf = 1.15f;
    unsigned pu;
    memcpy(&pu, &pivf, sizeof(pu));
    unsigned PIV = (pu & 0x80000000u) ? ~pu : (pu | 0x80000000u);

    if (ws_size >= (size_t)n * sizeof(float)) {
        float* boost = (float*)d_ws;
        boost_kernel<<<(n + 255) / 256, 256, 0, stream>>>(dc, boost, n);
        kwta_scan<true><<<rows, TPB, 0, stream>>>(x, boost, dc, out, n, k, PIV);
    } else {
        kwta_scan<false><<<rows, TPB, 0, stream>>>(x, nullptr, dc, out, n, k, PIV);
    }
}